// Round 1
// baseline (302.937 us; speedup 1.0000x reference)
//
#include <hip/hip_runtime.h>

// ---------------- types ----------------
typedef __attribute__((ext_vector_type(8))) __bf16 bf16x8;
typedef __attribute__((ext_vector_type(4))) float f32x4;
typedef __attribute__((ext_vector_type(4))) unsigned short ushort4v;

__device__ __forceinline__ unsigned short f2bf(float f) {
  unsigned u = __builtin_bit_cast(unsigned, f);
  u += 0x7fffu + ((u >> 16) & 1u);   // RNE
  return (unsigned short)(u >> 16);
}

__device__ __forceinline__ void gload16(const void* g, void* l) {
  __builtin_amdgcn_global_load_lds(
      (const __attribute__((address_space(1))) void*)g,
      (__attribute__((address_space(3))) void*)l, 16, 0, 0);
}

// ---------------- rope tables: cos/sin (2048 x 32) ----------------
__global__ __launch_bounds__(256) void rope_tab_k(float* cosT, float* sinT) {
  const int idx = blockIdx.x * 256 + threadIdx.x;   // 65536 total
  const int s = idx >> 5, j = idx & 31;
  const float freq = powf(10000.f, -(float)(2 * j) * (1.f / 64.f));
  const float ang = (float)s * freq;
  cosT[idx] = cosf(ang);
  sinT[idx] = sinf(ang);
}

// ---------------- convert fp32 -> bf16 (x, wq|wk|wv concat, wo) ----------------
__global__ __launch_bounds__(256) void convert_k(
    const float* __restrict__ x, const float* __restrict__ wq,
    const float* __restrict__ wk, const float* __restrict__ wv,
    const float* __restrict__ wo,
    unsigned short* __restrict__ xb, unsigned short* __restrict__ wqkv,
    unsigned short* __restrict__ wob) {
  const size_t i = ((size_t)blockIdx.x * 256 + threadIdx.x) * 4;
  const float* src; unsigned short* dst; size_t off;
  if (i < 4194304)      { src = x;  dst = xb;              off = i; }
  else if (i < 5242880) { src = wq; dst = wqkv;            off = i - 4194304; }
  else if (i < 6291456) { src = wk; dst = wqkv + 1048576;  off = i - 5242880; }
  else if (i < 7340032) { src = wv; dst = wqkv + 2097152;  off = i - 6291456; }
  else                  { src = wo; dst = wob;             off = i - 7340032; }
  f32x4 v = *(const f32x4*)(src + off);
  ushort4v o;
  o[0] = f2bf(v[0]); o[1] = f2bf(v[1]); o[2] = f2bf(v[2]); o[3] = f2bf(v[3]);
  *(ushort4v*)(dst + off) = o;
}

// ---------------- GEMM C = A @ B^T, A:(M,K) bf16, B:(N,K) bf16 ----------------
// 128x128 tile, BK=64, 256 threads (4 waves, 2x2 of 64x64), 16x16x32 MFMA.
// LDS XOR-swizzle ((row&7)<<4) with pre-swizzled global_load_lds source.
// EPI 0: QKV epilogue (bias + RoPE + 1/8 on Q, writes Qr/Kr head-major, Vt d-major)
// EPI 1: bias + fp32 store
template <int EPI>
__global__ __launch_bounds__(256) void gemm_bt_k(
    const unsigned short* __restrict__ A, const unsigned short* __restrict__ B,
    int M, int N, int K,
    unsigned short* __restrict__ Qr, unsigned short* __restrict__ Kr,
    unsigned short* __restrict__ Vt,
    const float* __restrict__ bq, const float* __restrict__ bk,
    const float* __restrict__ bvv,
    const float* __restrict__ cosT, const float* __restrict__ sinT,
    float* __restrict__ Cout, const float* __restrict__ bias) {
  __shared__ char smem[32768];   // A tile 16KB | B tile 16KB
  const int t = threadIdx.x;
  const int wave = t >> 6, lane = t & 63;
  const int l15 = lane & 15, g = lane >> 4;
  const int nt = N >> 7;
  const int mb = (blockIdx.x / nt) << 7;
  const int nb = (blockIdx.x % nt) << 7;
  const int wm = (wave >> 1) << 6;
  const int wn = (wave & 1) << 6;

  const f32x4 zv = {0.f, 0.f, 0.f, 0.f};
  f32x4 acc[4][4];
#pragma unroll
  for (int i = 0; i < 4; i++)
#pragma unroll
    for (int j = 0; j < 4; j++) acc[i][j] = zv;

  for (int kt = 0; kt < K; kt += 64) {
#pragma unroll
    for (int i = 0; i < 4; i++) {
      const int lin = t * 16 + i * 4096;
      const int r = lin >> 7;
      const int cb = (lin & 127) ^ ((r & 7) << 4);   // pre-swizzled source col-byte
      gload16((const char*)A + ((size_t)(mb + r) * K + kt) * 2 + cb,
              smem + i * 4096 + wave * 1024);
      gload16((const char*)B + ((size_t)(nb + r) * K + kt) * 2 + cb,
              smem + 16384 + i * 4096 + wave * 1024);
    }
    __syncthreads();

    bf16x8 af[4][2], bfr[4][2];
    const int sw = (l15 & 7) << 4;
#pragma unroll
    for (int mf = 0; mf < 4; mf++) {
      const int r = wm + mf * 16 + l15;
      const int r2 = wn + mf * 16 + l15;
#pragma unroll
      for (int kf = 0; kf < 2; kf++) {
        af[mf][kf]  = *(const bf16x8*)(smem + r * 128 + ((kf * 64 + g * 16) ^ sw));
        bfr[mf][kf] = *(const bf16x8*)(smem + 16384 + r2 * 128 + ((kf * 64 + g * 16) ^ sw));
      }
    }
#pragma unroll
    for (int mf = 0; mf < 4; mf++)
#pragma unroll
      for (int nf = 0; nf < 4; nf++) {
        acc[mf][nf] = __builtin_amdgcn_mfma_f32_16x16x32_bf16(af[mf][0], bfr[nf][0], acc[mf][nf], 0, 0, 0);
        acc[mf][nf] = __builtin_amdgcn_mfma_f32_16x16x32_bf16(af[mf][1], bfr[nf][1], acc[mf][nf], 0, 0, 0);
      }
    __syncthreads();
  }

  // epilogue: lane element (mf,nf,r): row = mb+wm+mf*16+g*4+r, col = nb+wn+nf*16+l15
#pragma unroll
  for (int mf = 0; mf < 4; mf++) {
#pragma unroll
    for (int nf = 0; nf < 4; nf++) {
      const int row0 = mb + wm + mf * 16 + g * 4;
      const int col = nb + wn + nf * 16 + l15;
      if (EPI == 1) {
        const float bsv = bias[col];
#pragma unroll
        for (int r = 0; r < 4; r++)
          Cout[(size_t)(row0 + r) * N + col] = acc[mf][nf][r] + bsv;
      } else {
        const int region = col >> 10;           // uniform per block (128 | 1024)
        const int cc = col & 1023;
        const int h = cc >> 6, d = cc & 63;
        const float bias_v = (region == 0 ? bq : (region == 1 ? bk : bvv))[cc];
        if (region < 2) {
          unsigned short* Ob = (region == 0 ? Qr : Kr);
          const float scl = (region == 0) ? 0.125f : 1.0f;
#pragma unroll
          for (int r = 0; r < 4; r++) {
            const int row = row0 + r;
            const int s = row & 2047;
            const int b = row >> 11;
            const float v = acc[mf][nf][r] + bias_v;
            const float p = __shfl_xor(v, 1);
            const float c = cosT[s * 32 + (d >> 1)];
            const float sn = sinT[s * 32 + (d >> 1)];
            float o = (d & 1) ? (v * c + p * sn) : (v * c - p * sn);
            o *= scl;
            Ob[((size_t)(b * 16 + h) * 2048 + s) * 64 + d] = f2bf(o);
          }
        } else {
          ushort4v w;
#pragma unroll
          for (int r = 0; r < 4; r++) w[r] = f2bf(acc[mf][nf][r] + bias_v);
          const int s = row0 & 2047;
          const int b = row0 >> 11;
          *(ushort4v*)(Vt + ((size_t)(b * 16 + h) * 64 + d) * 2048 + s) = w;
        }
      }
    }
  }
}

// ---------------- flash attention ----------------
// grid: 1024 blocks (bh = bid&31 fast for XCD L2 locality), 4 waves/block,
// each wave: 16 q-rows, swapped QK^T (S^T = K·Q^T) -> lane-local softmax
// (q = lane&15), O^T = V^T·P^T. P via per-wave swizzled LDS, no barriers.
__global__ __launch_bounds__(256) void flash_k(
    const unsigned short* __restrict__ Qr, const unsigned short* __restrict__ Kr,
    const unsigned short* __restrict__ Vt, unsigned short* __restrict__ Oa) {
  __shared__ char plds[4][1024];                 // per-wave 16x32 bf16
  const int bid = blockIdx.x;
  const int bh = bid & 31;
  const int qt = bid >> 5;
  const int wave = threadIdx.x >> 6, lane = threadIdx.x & 63;
  const int l15 = lane & 15, g = lane >> 4;
  char* pbuf = plds[wave];
  const int q0 = qt * 64 + wave * 16;
  const unsigned short* Qb = Qr + ((size_t)bh * 2048 + q0) * 64;
  const unsigned short* Kb = Kr + (size_t)bh * 2048 * 64;
  const unsigned short* Vb = Vt + (size_t)bh * 64 * 2048;

  const bf16x8 qf0 = *(const bf16x8*)(Qb + l15 * 64 + g * 8);
  const bf16x8 qf1 = *(const bf16x8*)(Qb + l15 * 64 + g * 8 + 32);

  const f32x4 zv = {0.f, 0.f, 0.f, 0.f};
  f32x4 ot[4];
#pragma unroll
  for (int i = 0; i < 4; i++) ot[i] = zv;
  float m = -1e30f, lsum = 0.f;
  const int swz = (l15 & 3) << 4;

  for (int kv0 = 0; kv0 < 2048; kv0 += 32) {
    f32x4 st[2];
#pragma unroll
    for (int s = 0; s < 2; s++) {
      const unsigned short* kp = Kb + (size_t)(kv0 + s * 16 + l15) * 64 + g * 8;
      const bf16x8 k0 = *(const bf16x8*)(kp);
      const bf16x8 k1 = *(const bf16x8*)(kp + 32);
      f32x4 a = __builtin_amdgcn_mfma_f32_16x16x32_bf16(k0, qf0, zv, 0, 0, 0);
      st[s] = __builtin_amdgcn_mfma_f32_16x16x32_bf16(k1, qf1, a, 0, 0, 0);
    }
    // row (per-q) max across kv: in-lane 8 + xor 16/32 across groups
    float tmax = st[0][0];
#pragma unroll
    for (int e = 1; e < 4; e++) tmax = fmaxf(tmax, st[0][e]);
#pragma unroll
    for (int e = 0; e < 4; e++) tmax = fmaxf(tmax, st[1][e]);
    tmax = fmaxf(tmax, __shfl_xor(tmax, 16));
    tmax = fmaxf(tmax, __shfl_xor(tmax, 32));
    const float mn = fmaxf(m, tmax);
    float pr[8];
    float ts = 0.f;
#pragma unroll
    for (int s = 0; s < 2; s++)
#pragma unroll
      for (int e = 0; e < 4; e++) {
        const float p = __expf(st[s][e] - mn);
        pr[s * 4 + e] = p;
        ts += p;
      }
    ts += __shfl_xor(ts, 16);
    ts += __shfl_xor(ts, 32);
    const float alpha = __expf(m - mn);
    lsum = lsum * alpha + ts;
    m = mn;
#pragma unroll
    for (int i = 0; i < 4; i++) {
      ot[i][0] *= alpha; ot[i][1] *= alpha; ot[i][2] *= alpha; ot[i][3] *= alpha;
    }
    // P^T -> LDS [q=16][kv=32] bf16, byte ^= ((q&3)<<4)
#pragma unroll
    for (int s = 0; s < 2; s++) {
      ushort4v w;
#pragma unroll
      for (int e = 0; e < 4; e++) w[e] = f2bf(pr[s * 4 + e]);
      *(ushort4v*)(pbuf + ((l15 * 64 + s * 32 + g * 8) ^ swz)) = w;
    }
    asm volatile("" ::: "memory");   // keep write->read order (wave-synchronous)
    const bf16x8 pb = *(const bf16x8*)(pbuf + ((l15 * 64 + g * 16) ^ swz));
#pragma unroll
    for (int dc = 0; dc < 4; dc++) {
      const bf16x8 va = *(const bf16x8*)(Vb + (size_t)(dc * 16 + l15) * 2048 + kv0 + g * 8);
      ot[dc] = __builtin_amdgcn_mfma_f32_16x16x32_bf16(va, pb, ot[dc], 0, 0, 0);
    }
  }
  const float inv = 1.f / lsum;
  const int b = bh >> 4, h = bh & 15;
  const size_t rowbase = ((size_t)(b * 2048 + q0 + l15)) * 1024 + h * 64;
#pragma unroll
  for (int dc = 0; dc < 4; dc++) {
    ushort4v w;
#pragma unroll
    for (int r = 0; r < 4; r++) w[r] = f2bf(ot[dc][r] * inv);
    *(ushort4v*)(Oa + rowbase + dc * 16 + g * 4) = w;
  }
}

// ---------------- launch ----------------
extern "C" void kernel_launch(void* const* d_in, const int* in_sizes, int n_in,
                              void* d_out, int out_size, void* d_ws, size_t ws_size,
                              hipStream_t stream) {
  const float* x  = (const float*)d_in[0];
  const float* wq = (const float*)d_in[1];
  const float* bq = (const float*)d_in[2];
  const float* wk = (const float*)d_in[3];
  const float* bk = (const float*)d_in[4];
  const float* wv = (const float*)d_in[5];
  const float* bv = (const float*)d_in[6];
  const float* wo = (const float*)d_in[7];
  const float* bo = (const float*)d_in[8];
  float* out = (float*)d_out;
  char* ws = (char*)d_ws;

  unsigned short* xb   = (unsigned short*)(ws);              //  8 MB
  unsigned short* wqkv = (unsigned short*)(ws + 8388608);    //  6 MB
  unsigned short* wob  = (unsigned short*)(ws + 14680064);   //  2 MB
  float* cosT          = (float*)(ws + 16777216);            // 256 KB
  float* sinT          = (float*)(ws + 17039360);            // 256 KB
  unsigned short* Qr   = (unsigned short*)(ws + 17301504);   //  8 MB (B,H,S,D)
  unsigned short* Kr   = (unsigned short*)(ws + 25690112);   //  8 MB (B,H,S,D)
  unsigned short* Vt   = (unsigned short*)(ws + 34078720);   //  8 MB (B,H,D,S)
  unsigned short* Oa   = (unsigned short*)(ws + 42467328);   //  8 MB (B,S,DM)

  rope_tab_k<<<dim3(256), dim3(256), 0, stream>>>(cosT, sinT);
  convert_k<<<dim3(8192), dim3(256), 0, stream>>>(x, wq, wk, wv, wo, xb, wqkv, wob);
  gemm_bt_k<0><<<dim3(32 * 24), dim3(256), 0, stream>>>(
      xb, wqkv, 4096, 3072, 1024, Qr, Kr, Vt, bq, bk, bv, cosT, sinT,
      (float*)nullptr, (const float*)nullptr);
  flash_k<<<dim3(1024), dim3(256), 0, stream>>>(Qr, Kr, Vt, Oa);
  gemm_bt_k<1><<<dim3(32 * 8), dim3(256), 0, stream>>>(
      Oa, wob, 4096, 1024, 1024,
      (unsigned short*)nullptr, (unsigned short*)nullptr, (unsigned short*)nullptr,
      (const float*)nullptr, (const float*)nullptr, (const float*)nullptr,
      cosT, sinT, out, bo);
}

// Round 2
// 301.467 us; speedup vs baseline: 1.0049x; 1.0049x over previous
//
#include <hip/hip_runtime.h>

// ---------------- types ----------------
typedef __attribute__((ext_vector_type(8))) __bf16 bf16x8;
typedef __attribute__((ext_vector_type(4))) float f32x4;
typedef __attribute__((ext_vector_type(4))) unsigned short ushort4v;

__device__ __forceinline__ unsigned short f2bf(float f) {
  unsigned u = __builtin_bit_cast(unsigned, f);
  u += 0x7fffu + ((u >> 16) & 1u);   // RNE
  return (unsigned short)(u >> 16);
}

__device__ __forceinline__ void gload16(const void* g, void* l) {
  __builtin_amdgcn_global_load_lds(
      (const __attribute__((address_space(1))) void*)g,
      (__attribute__((address_space(3))) void*)l, 16, 0, 0);
}

// ---------------- rope tables: cos/sin (2048 x 32) ----------------
__global__ __launch_bounds__(256) void rope_tab_k(float* cosT, float* sinT) {
  const int idx = blockIdx.x * 256 + threadIdx.x;   // 65536 total
  const int s = idx >> 5, j = idx & 31;
  const float freq = powf(10000.f, -(float)(2 * j) * (1.f / 64.f));
  const float ang = (float)s * freq;
  cosT[idx] = cosf(ang);
  sinT[idx] = sinf(ang);
}

// ---------------- convert fp32 -> bf16 (x, wq|wk|wv concat, wo) ----------------
__global__ __launch_bounds__(256) void convert_k(
    const float* __restrict__ x, const float* __restrict__ wq,
    const float* __restrict__ wk, const float* __restrict__ wv,
    const float* __restrict__ wo,
    unsigned short* __restrict__ xb, unsigned short* __restrict__ wqkv,
    unsigned short* __restrict__ wob) {
  const size_t i = ((size_t)blockIdx.x * 256 + threadIdx.x) * 4;
  const float* src; unsigned short* dst; size_t off;
  if (i < 4194304)      { src = x;  dst = xb;              off = i; }
  else if (i < 5242880) { src = wq; dst = wqkv;            off = i - 4194304; }
  else if (i < 6291456) { src = wk; dst = wqkv + 1048576;  off = i - 5242880; }
  else if (i < 7340032) { src = wv; dst = wqkv + 2097152;  off = i - 6291456; }
  else                  { src = wo; dst = wob;             off = i - 7340032; }
  f32x4 v = *(const f32x4*)(src + off);
  ushort4v o;
  o[0] = f2bf(v[0]); o[1] = f2bf(v[1]); o[2] = f2bf(v[2]); o[3] = f2bf(v[3]);
  *(ushort4v*)(dst + off) = o;
}

// ---------------- GEMM C = A @ B^T, A:(M,K) bf16, B:(N,K) bf16 ----------------
// 128x128 tile, BK=64, 256 threads (4 waves, 2x2 of 64x64), 16x16x32 MFMA.
// LDS XOR-swizzle ((row&7)<<4) with pre-swizzled global_load_lds source.
// EPI 0: QKV epilogue (bias + RoPE + scale on Q, writes Qr/Kr head-major, Vt d-major)
// EPI 1: bias + fp32 store
template <int EPI>
__global__ __launch_bounds__(256) void gemm_bt_k(
    const unsigned short* __restrict__ A, const unsigned short* __restrict__ B,
    int M, int N, int K,
    unsigned short* __restrict__ Qr, unsigned short* __restrict__ Kr,
    unsigned short* __restrict__ Vt,
    const float* __restrict__ bq, const float* __restrict__ bk,
    const float* __restrict__ bvv,
    const float* __restrict__ cosT, const float* __restrict__ sinT,
    float* __restrict__ Cout, const float* __restrict__ bias) {
  __shared__ char smem[32768];   // A tile 16KB | B tile 16KB
  const int t = threadIdx.x;
  const int wave = t >> 6, lane = t & 63;
  const int l15 = lane & 15, g = lane >> 4;
  const int nt = N >> 7;
  const int mb = (blockIdx.x / nt) << 7;
  const int nb = (blockIdx.x % nt) << 7;
  const int wm = (wave >> 1) << 6;
  const int wn = (wave & 1) << 6;

  const f32x4 zv = {0.f, 0.f, 0.f, 0.f};
  f32x4 acc[4][4];
#pragma unroll
  for (int i = 0; i < 4; i++)
#pragma unroll
    for (int j = 0; j < 4; j++) acc[i][j] = zv;

  for (int kt = 0; kt < K; kt += 64) {
#pragma unroll
    for (int i = 0; i < 4; i++) {
      const int lin = t * 16 + i * 4096;
      const int r = lin >> 7;
      const int cb = (lin & 127) ^ ((r & 7) << 4);   // pre-swizzled source col-byte
      gload16((const char*)A + ((size_t)(mb + r) * K + kt) * 2 + cb,
              smem + i * 4096 + wave * 1024);
      gload16((const char*)B + ((size_t)(nb + r) * K + kt) * 2 + cb,
              smem + 16384 + i * 4096 + wave * 1024);
    }
    __syncthreads();

    bf16x8 af[4][2], bfr[4][2];
    const int sw = (l15 & 7) << 4;
#pragma unroll
    for (int mf = 0; mf < 4; mf++) {
      const int r = wm + mf * 16 + l15;
      const int r2 = wn + mf * 16 + l15;
#pragma unroll
      for (int kf = 0; kf < 2; kf++) {
        af[mf][kf]  = *(const bf16x8*)(smem + r * 128 + ((kf * 64 + g * 16) ^ sw));
        bfr[mf][kf] = *(const bf16x8*)(smem + 16384 + r2 * 128 + ((kf * 64 + g * 16) ^ sw));
      }
    }
#pragma unroll
    for (int mf = 0; mf < 4; mf++)
#pragma unroll
      for (int nf = 0; nf < 4; nf++) {
        acc[mf][nf] = __builtin_amdgcn_mfma_f32_16x16x32_bf16(af[mf][0], bfr[nf][0], acc[mf][nf], 0, 0, 0);
        acc[mf][nf] = __builtin_amdgcn_mfma_f32_16x16x32_bf16(af[mf][1], bfr[nf][1], acc[mf][nf], 0, 0, 0);
      }
    __syncthreads();
  }

  // epilogue: lane element (mf,nf,r): row = mb+wm+mf*16+g*4+r, col = nb+wn+nf*16+l15
#pragma unroll
  for (int mf = 0; mf < 4; mf++) {
#pragma unroll
    for (int nf = 0; nf < 4; nf++) {
      const int row0 = mb + wm + mf * 16 + g * 4;
      const int col = nb + wn + nf * 16 + l15;
      if (EPI == 1) {
        const float bsv = bias[col];
#pragma unroll
        for (int r = 0; r < 4; r++)
          Cout[(size_t)(row0 + r) * N + col] = acc[mf][nf][r] + bsv;
      } else {
        const int region = col >> 10;           // uniform per block (128 | 1024)
        const int cc = col & 1023;
        const int h = cc >> 6, d = cc & 63;
        const float bias_v = (region == 0 ? bq : (region == 1 ? bk : bvv))[cc];
        if (region < 2) {
          unsigned short* Ob = (region == 0 ? Qr : Kr);
          // Q gets 1/sqrt(64) * log2(e) baked in (flash works in exp2 domain)
          const float scl = (region == 0) ? 0.180336880111120425f : 1.0f;
#pragma unroll
          for (int r = 0; r < 4; r++) {
            const int row = row0 + r;
            const int s = row & 2047;
            const int b = row >> 11;
            const float v = acc[mf][nf][r] + bias_v;
            const float p = __shfl_xor(v, 1);
            const float c = cosT[s * 32 + (d >> 1)];
            const float sn = sinT[s * 32 + (d >> 1)];
            float o = (d & 1) ? (v * c + p * sn) : (v * c - p * sn);
            o *= scl;
            Ob[((size_t)(b * 16 + h) * 2048 + s) * 64 + d] = f2bf(o);
          }
        } else {
          ushort4v w;
#pragma unroll
          for (int r = 0; r < 4; r++) w[r] = f2bf(acc[mf][nf][r] + bias_v);
          const int s = row0 & 2047;
          const int b = row0 >> 11;
          *(ushort4v*)(Vt + ((size_t)(b * 16 + h) * 64 + d) * 2048 + s) = w;
        }
      }
    }
  }
}

// ---------------- flash attention v2 ----------------
// grid: 1024 blocks (bh = bid&31 -> all blocks of a head land on one XCD),
// 4 waves/block, wave = 16 q-rows, KVBLK=64 (16 MFMA/iter), swapped QK^T,
// exp2-domain softmax (scale*log2e baked into Q), lane-local partial lsum,
// defer-max rescale (THR=8), P via per-wave 16x64 XOR-swizzled LDS.
__global__ __launch_bounds__(256, 4) void flash_k(
    const unsigned short* __restrict__ Qr, const unsigned short* __restrict__ Kr,
    const unsigned short* __restrict__ Vt, unsigned short* __restrict__ Oa) {
  __shared__ char plds[4][2048];                 // per-wave 16x64 bf16, 128B rows
  const int bid = blockIdx.x;
  const int bh = bid & 31;
  const int qt = bid >> 5;
  const int wave = threadIdx.x >> 6, lane = threadIdx.x & 63;
  const int l15 = lane & 15, g = lane >> 4;
  char* pbuf = plds[wave];
  const int q0 = qt * 64 + wave * 16;
  const unsigned short* Qb = Qr + ((size_t)bh * 2048 + q0) * 64;
  const unsigned short* Kb = Kr + (size_t)bh * 2048 * 64;
  const unsigned short* Vb = Vt + (size_t)bh * 64 * 2048;

  const bf16x8 qf0 = *(const bf16x8*)(Qb + l15 * 64 + g * 8);
  const bf16x8 qf1 = *(const bf16x8*)(Qb + l15 * 64 + g * 8 + 32);

  const f32x4 zv = {0.f, 0.f, 0.f, 0.f};
  f32x4 ot[4];
#pragma unroll
  for (int i = 0; i < 4; i++) ot[i] = zv;
  float m = -1e30f, lsum = 0.f;
  const int swz = (l15 & 7) << 4;

  for (int kv0 = 0; kv0 < 2048; kv0 += 64) {
    // --- K loads first (QK waits only on these), then V (stay in flight) ---
    bf16x8 kf[4][2];
#pragma unroll
    for (int s = 0; s < 4; s++) {
      const unsigned short* kp = Kb + (size_t)(kv0 + s * 16 + l15) * 64 + g * 8;
      kf[s][0] = *(const bf16x8*)(kp);
      kf[s][1] = *(const bf16x8*)(kp + 32);
    }
    bf16x8 vf[2][4];
#pragma unroll
    for (int h = 0; h < 2; h++)
#pragma unroll
      for (int dc = 0; dc < 4; dc++)
        vf[h][dc] = *(const bf16x8*)(Vb + (size_t)(dc * 16 + l15) * 2048 +
                                     kv0 + h * 32 + g * 8);
    // --- QK^T: lane holds S[q=l15][kv = kv0 + s*16 + g*4 + e] ---
    f32x4 st[4];
#pragma unroll
    for (int s = 0; s < 4; s++) {
      f32x4 a = __builtin_amdgcn_mfma_f32_16x16x32_bf16(kf[s][0], qf0, zv, 0, 0, 0);
      st[s] = __builtin_amdgcn_mfma_f32_16x16x32_bf16(kf[s][1], qf1, a, 0, 0, 0);
    }
    // --- per-q max: 15 in-lane + 2 shfl across g-groups ---
    float tmax = st[0][0];
#pragma unroll
    for (int s = 0; s < 4; s++)
#pragma unroll
      for (int e = 0; e < 4; e++) tmax = fmaxf(tmax, st[s][e]);
    tmax = fmaxf(tmax, __shfl_xor(tmax, 16));
    tmax = fmaxf(tmax, __shfl_xor(tmax, 32));
    // --- defer-max: only rescale when some row grew past m+8 (exp2 domain) ---
    if (!__all(tmax <= m + 8.0f)) {
      const float mn = fmaxf(m, tmax);
      const float al = __builtin_amdgcn_exp2f(m - mn);
      lsum *= al;
#pragma unroll
      for (int i = 0; i < 4; i++) {
        ot[i][0] *= al; ot[i][1] *= al; ot[i][2] *= al; ot[i][3] *= al;
      }
      m = mn;
    }
    // --- P = exp2(S - m); lane-local partial lsum (cross-lane deferred) ---
#pragma unroll
    for (int s = 0; s < 4; s++)
#pragma unroll
      for (int e = 0; e < 4; e++) {
        const float p = __builtin_amdgcn_exp2f(st[s][e] - m);
        st[s][e] = p;
        lsum += p;
      }
    // --- P -> LDS [q=l15 row, 128B][kv byte col] ^ ((l15&7)<<4) ---
#pragma unroll
    for (int s = 0; s < 4; s++) {
      ushort4v w;
#pragma unroll
      for (int e = 0; e < 4; e++) w[e] = f2bf(st[s][e]);
      *(ushort4v*)(pbuf + ((l15 * 128 + s * 32 + g * 8) ^ swz)) = w;
    }
    asm volatile("" ::: "memory");   // wave-synchronous write->read order
    // --- PV: O^T += V^T · P^T ---
#pragma unroll
    for (int h = 0; h < 2; h++) {
      const bf16x8 pb = *(const bf16x8*)(pbuf + ((l15 * 128 + h * 64 + g * 16) ^ swz));
#pragma unroll
      for (int dc = 0; dc < 4; dc++)
        ot[dc] = __builtin_amdgcn_mfma_f32_16x16x32_bf16(vf[h][dc], pb, ot[dc], 0, 0, 0);
    }
  }
  lsum += __shfl_xor(lsum, 16);
  lsum += __shfl_xor(lsum, 32);
  const float inv = 1.f / lsum;
  const int b = bh >> 4, h = bh & 15;
  const size_t rowbase = ((size_t)(b * 2048 + q0 + l15)) * 1024 + h * 64;
#pragma unroll
  for (int dc = 0; dc < 4; dc++) {
    ushort4v w;
#pragma unroll
    for (int r = 0; r < 4; r++) w[r] = f2bf(ot[dc][r] * inv);
    *(ushort4v*)(Oa + rowbase + dc * 16 + g * 4) = w;
  }
}

// ---------------- launch ----------------
extern "C" void kernel_launch(void* const* d_in, const int* in_sizes, int n_in,
                              void* d_out, int out_size, void* d_ws, size_t ws_size,
                              hipStream_t stream) {
  const float* x  = (const float*)d_in[0];
  const float* wq = (const float*)d_in[1];
  const float* bq = (const float*)d_in[2];
  const float* wk = (const float*)d_in[3];
  const float* bk = (const float*)d_in[4];
  const float* wv = (const float*)d_in[5];
  const float* bv = (const float*)d_in[6];
  const float* wo = (const float*)d_in[7];
  const float* bo = (const float*)d_in[8];
  float* out = (float*)d_out;
  char* ws = (char*)d_ws;

  unsigned short* xb   = (unsigned short*)(ws);              //  8 MB
  unsigned short* wqkv = (unsigned short*)(ws + 8388608);    //  6 MB
  unsigned short* wob  = (unsigned short*)(ws + 14680064);   //  2 MB
  float* cosT          = (float*)(ws + 16777216);            // 256 KB
  float* sinT          = (float*)(ws + 17039360);            // 256 KB
  unsigned short* Qr   = (unsigned short*)(ws + 17301504);   //  8 MB (B,H,S,D)
  unsigned short* Kr   = (unsigned short*)(ws + 25690112);   //  8 MB (B,H,S,D)
  unsigned short* Vt   = (unsigned short*)(ws + 34078720);   //  8 MB (B,H,D,S)
  unsigned short* Oa   = (unsigned short*)(ws + 42467328);   //  8 MB (B,S,DM)

  rope_tab_k<<<dim3(256), dim3(256), 0, stream>>>(cosT, sinT);
  convert_k<<<dim3(8192), dim3(256), 0, stream>>>(x, wq, wk, wv, wo, xb, wqkv, wob);
  gemm_bt_k<0><<<dim3(32 * 24), dim3(256), 0, stream>>>(
      xb, wqkv, 4096, 3072, 1024, Qr, Kr, Vt, bq, bk, bv, cosT, sinT,
      (float*)nullptr, (const float*)nullptr);
  flash_k<<<dim3(1024), dim3(256), 0, stream>>>(Qr, Kr, Vt, Oa);
  gemm_bt_k<1><<<dim3(32 * 8), dim3(256), 0, stream>>>(
      Oa, wob, 4096, 1024, 1024,
      (unsigned short*)nullptr, (unsigned short*)nullptr, (unsigned short*)nullptr,
      (const float*)nullptr, (const float*)nullptr, (const float*)nullptr,
      cosT, sinT, out, bo);
}

// Round 3
// 138.153 us; speedup vs baseline: 2.1928x; 2.1821x over previous
//
#include <hip/hip_runtime.h>

// ---------------- types ----------------
typedef __attribute__((ext_vector_type(8))) __bf16 bf16x8;
typedef __attribute__((ext_vector_type(4))) float f32x4;
typedef __attribute__((ext_vector_type(4))) unsigned short ushort4v;

__device__ __forceinline__ unsigned short f2bf(float f) {
  unsigned u = __builtin_bit_cast(unsigned, f);
  u += 0x7fffu + ((u >> 16) & 1u);   // RNE
  return (unsigned short)(u >> 16);
}

__device__ __forceinline__ void gload16(const void* g, void* l) {
  __builtin_amdgcn_global_load_lds(
      (const __attribute__((address_space(1))) void*)g,
      (__attribute__((address_space(3))) void*)l, 16, 0, 0);
}

// ---------------- rope tables: cos/sin (2048 x 32) ----------------
__global__ __launch_bounds__(256) void rope_tab_k(float* cosT, float* sinT) {
  const int idx = blockIdx.x * 256 + threadIdx.x;   // 65536 total
  const int s = idx >> 5, j = idx & 31;
  const float freq = powf(10000.f, -(float)(2 * j) * (1.f / 64.f));
  const float ang = (float)s * freq;
  cosT[idx] = cosf(ang);
  sinT[idx] = sinf(ang);
}

// ---------------- convert fp32 -> bf16 (x, wq|wk|wv concat, wo) ----------------
__global__ __launch_bounds__(256) void convert_k(
    const float* __restrict__ x, const float* __restrict__ wq,
    const float* __restrict__ wk, const float* __restrict__ wv,
    const float* __restrict__ wo,
    unsigned short* __restrict__ xb, unsigned short* __restrict__ wqkv,
    unsigned short* __restrict__ wob) {
  const size_t i = ((size_t)blockIdx.x * 256 + threadIdx.x) * 4;
  const float* src; unsigned short* dst; size_t off;
  if (i < 4194304)      { src = x;  dst = xb;              off = i; }
  else if (i < 5242880) { src = wq; dst = wqkv;            off = i - 4194304; }
  else if (i < 6291456) { src = wk; dst = wqkv + 1048576;  off = i - 5242880; }
  else if (i < 7340032) { src = wv; dst = wqkv + 2097152;  off = i - 6291456; }
  else                  { src = wo; dst = wob;             off = i - 7340032; }
  f32x4 v = *(const f32x4*)(src + off);
  ushort4v o;
  o[0] = f2bf(v[0]); o[1] = f2bf(v[1]); o[2] = f2bf(v[2]); o[3] = f2bf(v[3]);
  *(ushort4v*)(dst + off) = o;
}

// ---------------- GEMM C = A @ B^T, A:(M,K) bf16, B:(N,K) bf16 ----------------
// 128x128 tile, BK=64, 256 threads (4 waves, 2x2 of 64x64), 16x16x32 MFMA.
// LDS XOR-swizzle ((row&7)<<4) with pre-swizzled global_load_lds source.
// EPI 0: QKV epilogue (bias + RoPE + scale on Q, writes Qr/Kr head-major, Vt d-major)
// EPI 1: bias + fp32 store
template <int EPI>
__global__ __launch_bounds__(256) void gemm_bt_k(
    const unsigned short* __restrict__ A, const unsigned short* __restrict__ B,
    int M, int N, int K,
    unsigned short* __restrict__ Qr, unsigned short* __restrict__ Kr,
    unsigned short* __restrict__ Vt,
    const float* __restrict__ bq, const float* __restrict__ bk,
    const float* __restrict__ bvv,
    const float* __restrict__ cosT, const float* __restrict__ sinT,
    float* __restrict__ Cout, const float* __restrict__ bias) {
  __shared__ char smem[32768];   // A tile 16KB | B tile 16KB
  const int t = threadIdx.x;
  const int wave = t >> 6, lane = t & 63;
  const int l15 = lane & 15, g = lane >> 4;
  const int nt = N >> 7;
  const int mb = (blockIdx.x / nt) << 7;
  const int nb = (blockIdx.x % nt) << 7;
  const int wm = (wave >> 1) << 6;
  const int wn = (wave & 1) << 6;

  const f32x4 zv = {0.f, 0.f, 0.f, 0.f};
  f32x4 acc[4][4];
#pragma unroll
  for (int i = 0; i < 4; i++)
#pragma unroll
    for (int j = 0; j < 4; j++) acc[i][j] = zv;

  for (int kt = 0; kt < K; kt += 64) {
#pragma unroll
    for (int i = 0; i < 4; i++) {
      const int lin = t * 16 + i * 4096;
      const int r = lin >> 7;
      const int cb = (lin & 127) ^ ((r & 7) << 4);   // pre-swizzled source col-byte
      gload16((const char*)A + ((size_t)(mb + r) * K + kt) * 2 + cb,
              smem + i * 4096 + wave * 1024);
      gload16((const char*)B + ((size_t)(nb + r) * K + kt) * 2 + cb,
              smem + 16384 + i * 4096 + wave * 1024);
    }
    __syncthreads();

    bf16x8 af[4][2], bfr[4][2];
    const int sw = (l15 & 7) << 4;
#pragma unroll
    for (int mf = 0; mf < 4; mf++) {
      const int r = wm + mf * 16 + l15;
      const int r2 = wn + mf * 16 + l15;
#pragma unroll
      for (int kf = 0; kf < 2; kf++) {
        af[mf][kf]  = *(const bf16x8*)(smem + r * 128 + ((kf * 64 + g * 16) ^ sw));
        bfr[mf][kf] = *(const bf16x8*)(smem + 16384 + r2 * 128 + ((kf * 64 + g * 16) ^ sw));
      }
    }
#pragma unroll
    for (int mf = 0; mf < 4; mf++)
#pragma unroll
      for (int nf = 0; nf < 4; nf++) {
        acc[mf][nf] = __builtin_amdgcn_mfma_f32_16x16x32_bf16(af[mf][0], bfr[nf][0], acc[mf][nf], 0, 0, 0);
        acc[mf][nf] = __builtin_amdgcn_mfma_f32_16x16x32_bf16(af[mf][1], bfr[nf][1], acc[mf][nf], 0, 0, 0);
      }
    __syncthreads();
  }

  // epilogue: lane element (mf,nf,r): row = mb+wm+mf*16+g*4+r, col = nb+wn+nf*16+l15
#pragma unroll
  for (int mf = 0; mf < 4; mf++) {
#pragma unroll
    for (int nf = 0; nf < 4; nf++) {
      const int row0 = mb + wm + mf * 16 + g * 4;
      const int col = nb + wn + nf * 16 + l15;
      if (EPI == 1) {
        const float bsv = bias[col];
#pragma unroll
        for (int r = 0; r < 4; r++)
          Cout[(size_t)(row0 + r) * N + col] = acc[mf][nf][r] + bsv;
      } else {
        const int region = col >> 10;           // uniform per block (128 | 1024)
        const int cc = col & 1023;
        const int h = cc >> 6, d = cc & 63;
        const float bias_v = (region == 0 ? bq : (region == 1 ? bk : bvv))[cc];
        if (region < 2) {
          unsigned short* Ob = (region == 0 ? Qr : Kr);
          // Q gets 1/sqrt(64) * log2(e) baked in (flash works in exp2 domain)
          const float scl = (region == 0) ? 0.180336880111120425f : 1.0f;
#pragma unroll
          for (int r = 0; r < 4; r++) {
            const int row = row0 + r;
            const int s = row & 2047;
            const int b = row >> 11;
            const float v = acc[mf][nf][r] + bias_v;
            const float p = __shfl_xor(v, 1);
            const float c = cosT[s * 32 + (d >> 1)];
            const float sn = sinT[s * 32 + (d >> 1)];
            float o = (d & 1) ? (v * c + p * sn) : (v * c - p * sn);
            o *= scl;
            Ob[((size_t)(b * 16 + h) * 2048 + s) * 64 + d] = f2bf(o);
          }
        } else {
          ushort4v w;
#pragma unroll
          for (int r = 0; r < 4; r++) w[r] = f2bf(acc[mf][nf][r] + bias_v);
          const int s = row0 & 2047;
          const int b = row0 >> 11;
          *(ushort4v*)(Vt + ((size_t)(b * 16 + h) * 64 + d) * 2048 + s) = w;
        }
      }
    }
  }
}

// ---------------- flash attention v3 ----------------
// 512 blocks x 512 threads (8 waves). QBLK=128 (16 q-rows/wave), KVBLK=64.
// K-tile (64x64) + V^T-tile (64x64) staged once per block into LDS via
// global_load_lds (pre-swizzled source), double-buffered, 1 barrier/iter.
// bid decomposition gives each XCD 4 heads -> K/V working set 2MB fits L2.
// Swapped QK^T, exp2-domain softmax, defer-max, per-wave P LDS buffer.
__global__ __launch_bounds__(512, 4) void flash_k(
    const unsigned short* __restrict__ Qr, const unsigned short* __restrict__ Kr,
    const unsigned short* __restrict__ Vt, unsigned short* __restrict__ Oa) {
  __shared__ char smem[49152];   // [2][K 8KB | V 8KB] dbuf + 8 x 2KB P buffers
  const int bid = blockIdx.x;
  const int wi = bid >> 3;
  const int bh = ((bid & 7) << 2) | (wi & 3);   // XCD (bid&7) owns 4 heads
  const int qt = wi >> 2;                        // 0..15
  const int t = threadIdx.x;
  const int wave = t >> 6, lane = t & 63;
  const int l15 = lane & 15, g = lane >> 4;
  char* pbuf = smem + 32768 + wave * 2048;
  const int q0 = qt * 128 + wave * 16;
  const unsigned short* Qb = Qr + ((size_t)bh * 2048 + q0) * 64;
  const char* Kb = (const char*)(Kr + (size_t)bh * 2048 * 64);
  const char* Vb = (const char*)(Vt + (size_t)bh * 64 * 2048);

  // stage source decomposition (512 threads x 16B = 8KB per tile)
  const int srow = t >> 3;                                   // 0..63
  const int scb = ((t & 7) * 16) ^ ((srow & 7) << 4);        // pre-swizzled col byte

  const bf16x8 qf0 = *(const bf16x8*)(Qb + l15 * 64 + g * 8);
  const bf16x8 qf1 = *(const bf16x8*)(Qb + l15 * 64 + g * 8 + 32);

  const f32x4 zv = {0.f, 0.f, 0.f, 0.f};
  f32x4 ot[4];
#pragma unroll
  for (int i = 0; i < 4; i++) ot[i] = zv;
  float m = -1e30f, lsum = 0.f;
  const int sw = (l15 & 7) << 4;

  // prologue: stage tile 0
  {
    gload16(Kb + (size_t)srow * 128 + scb, smem + wave * 1024);
    gload16(Vb + (size_t)srow * 4096 + scb, smem + 8192 + wave * 1024);
  }
  __syncthreads();

  for (int it = 0; it < 32; ++it) {
    const int cur = it & 1;
    const char* kb = smem + cur * 16384;
    const char* vb = kb + 8192;
    if (it < 31) {   // stage next tile (loads stay in flight through compute)
      const int kvn = (it + 1) << 6;
      char* kd = smem + (cur ^ 1) * 16384;
      gload16(Kb + (size_t)(kvn + srow) * 128 + scb, kd + wave * 1024);
      gload16(Vb + (size_t)srow * 4096 + kvn * 2 + scb, kd + 8192 + wave * 1024);
    }
    // --- K frags from LDS + QK^T: lane holds S[q=l15][kv = s*16 + g*4 + e] ---
    f32x4 st[4];
#pragma unroll
    for (int s = 0; s < 4; s++) {
      const int rb = (s * 16 + l15) * 128;
      const bf16x8 k0 = *(const bf16x8*)(kb + rb + ((g * 16) ^ sw));
      const bf16x8 k1 = *(const bf16x8*)(kb + rb + ((64 + g * 16) ^ sw));
      f32x4 a = __builtin_amdgcn_mfma_f32_16x16x32_bf16(k0, qf0, zv, 0, 0, 0);
      st[s] = __builtin_amdgcn_mfma_f32_16x16x32_bf16(k1, qf1, a, 0, 0, 0);
    }
    // --- per-q max: in-lane + 2 shfl across g-groups ---
    float tmax = st[0][0];
#pragma unroll
    for (int s = 0; s < 4; s++)
#pragma unroll
      for (int e = 0; e < 4; e++) tmax = fmaxf(tmax, st[s][e]);
    tmax = fmaxf(tmax, __shfl_xor(tmax, 16));
    tmax = fmaxf(tmax, __shfl_xor(tmax, 32));
    // --- defer-max: rescale only when some row grew past m+8 (exp2 domain) ---
    if (!__all(tmax <= m + 8.0f)) {
      const float mn = fmaxf(m, tmax);
      const float al = __builtin_amdgcn_exp2f(m - mn);
      lsum *= al;
#pragma unroll
      for (int i = 0; i < 4; i++) {
        ot[i][0] *= al; ot[i][1] *= al; ot[i][2] *= al; ot[i][3] *= al;
      }
      m = mn;
    }
    // --- P = exp2(S - m); lane-local partial lsum ---
#pragma unroll
    for (int s = 0; s < 4; s++)
#pragma unroll
      for (int e = 0; e < 4; e++) {
        const float p = __builtin_amdgcn_exp2f(st[s][e] - m);
        st[s][e] = p;
        lsum += p;
      }
    // --- P -> per-wave LDS [q=l15, 128B row][kv byte] ^ sw ---
#pragma unroll
    for (int s = 0; s < 4; s++) {
      ushort4v w;
#pragma unroll
      for (int e = 0; e < 4; e++) w[e] = f2bf(st[s][e]);
      *(ushort4v*)(pbuf + ((l15 * 128 + s * 32 + g * 8) ^ sw)) = w;
    }
    asm volatile("" ::: "memory");   // wave-synchronous write->read order
    // --- V frags from LDS + PV: O^T += V^T . P^T ---
#pragma unroll
    for (int h = 0; h < 2; h++) {
      const bf16x8 pb = *(const bf16x8*)(pbuf + ((l15 * 128 + h * 64 + g * 16) ^ sw));
#pragma unroll
      for (int dc = 0; dc < 4; dc++) {
        const bf16x8 va = *(const bf16x8*)(vb + (dc * 16 + l15) * 128 + ((h * 64 + g * 16) ^ sw));
        ot[dc] = __builtin_amdgcn_mfma_f32_16x16x32_bf16(va, pb, ot[dc], 0, 0, 0);
      }
    }
    __syncthreads();   // stage loads landed (implicit vmcnt drain) + cur free
  }
  lsum += __shfl_xor(lsum, 16);
  lsum += __shfl_xor(lsum, 32);
  const float inv = 1.f / lsum;
  const int b = bh >> 4, h = bh & 15;
  const size_t rowbase = ((size_t)(b * 2048 + q0 + l15)) * 1024 + h * 64;
#pragma unroll
  for (int dc = 0; dc < 4; dc++) {
    ushort4v w;
#pragma unroll
    for (int r = 0; r < 4; r++) w[r] = f2bf(ot[dc][r] * inv);
    *(ushort4v*)(Oa + rowbase + dc * 16 + g * 4) = w;
  }
}

// ---------------- launch ----------------
extern "C" void kernel_launch(void* const* d_in, const int* in_sizes, int n_in,
                              void* d_out, int out_size, void* d_ws, size_t ws_size,
                              hipStream_t stream) {
  const float* x  = (const float*)d_in[0];
  const float* wq = (const float*)d_in[1];
  const float* bq = (const float*)d_in[2];
  const float* wk = (const float*)d_in[3];
  const float* bk = (const float*)d_in[4];
  const float* wv = (const float*)d_in[5];
  const float* bv = (const float*)d_in[6];
  const float* wo = (const float*)d_in[7];
  const float* bo = (const float*)d_in[8];
  float* out = (float*)d_out;
  char* ws = (char*)d_ws;

  unsigned short* xb   = (unsigned short*)(ws);              //  8 MB
  unsigned short* wqkv = (unsigned short*)(ws + 8388608);    //  6 MB
  unsigned short* wob  = (unsigned short*)(ws + 14680064);   //  2 MB
  float* cosT          = (float*)(ws + 16777216);            // 256 KB
  float* sinT          = (float*)(ws + 17039360);            // 256 KB
  unsigned short* Qr   = (unsigned short*)(ws + 17301504);   //  8 MB (B,H,S,D)
  unsigned short* Kr   = (unsigned short*)(ws + 25690112);   //  8 MB (B,H,S,D)
  unsigned short* Vt   = (unsigned short*)(ws + 34078720);   //  8 MB (B,H,D,S)
  unsigned short* Oa   = (unsigned short*)(ws + 42467328);   //  8 MB (B,S,DM)

  rope_tab_k<<<dim3(256), dim3(256), 0, stream>>>(cosT, sinT);
  convert_k<<<dim3(8192), dim3(256), 0, stream>>>(x, wq, wk, wv, wo, xb, wqkv, wob);
  gemm_bt_k<0><<<dim3(32 * 24), dim3(256), 0, stream>>>(
      xb, wqkv, 4096, 3072, 1024, Qr, Kr, Vt, bq, bk, bv, cosT, sinT,
      (float*)nullptr, (const float*)nullptr);
  flash_k<<<dim3(512), dim3(512), 0, stream>>>(Qr, Kr, Vt, Oa);
  gemm_bt_k<1><<<dim3(32 * 8), dim3(256), 0, stream>>>(
      Oa, wob, 4096, 1024, 1024,
      (unsigned short*)nullptr, (unsigned short*)nullptr, (unsigned short*)nullptr,
      (const float*)nullptr, (const float*)nullptr, (const float*)nullptr,
      cosT, sinT, out, bo);
}

// Round 5
// 136.844 us; speedup vs baseline: 2.2137x; 1.0096x over previous
//
#include <hip/hip_runtime.h>

// ---------------- types ----------------
typedef __attribute__((ext_vector_type(8))) __bf16 bf16x8;
typedef __attribute__((ext_vector_type(4))) __bf16 bf16x4;
typedef __attribute__((ext_vector_type(4))) float f32x4;
typedef __attribute__((ext_vector_type(4))) unsigned short ushort4v;

__device__ __forceinline__ unsigned short f2bf(float f) {
  unsigned u = __builtin_bit_cast(unsigned, f);
  u += 0x7fffu + ((u >> 16) & 1u);   // RNE
  return (unsigned short)(u >> 16);
}

__device__ __forceinline__ void gload16(const void* g, void* l) {
  __builtin_amdgcn_global_load_lds(
      (const __attribute__((address_space(1))) void*)g,
      (__attribute__((address_space(3))) void*)l, 16, 0, 0);
}

// ---------------- convert fp32 -> bf16 + rope tables (merged) ----------------
// grid = 8192 convert blocks + 256 rope blocks (65536 table entries)
__global__ __launch_bounds__(256) void convert_k(
    const float* __restrict__ x, const float* __restrict__ wq,
    const float* __restrict__ wk, const float* __restrict__ wv,
    const float* __restrict__ wo,
    unsigned short* __restrict__ xb, unsigned short* __restrict__ wqkv,
    unsigned short* __restrict__ wob, float* cosT, float* sinT) {
  if (blockIdx.x >= 8192) {   // rope tables: 256 blocks, 2048 x 32
    const int idx = (blockIdx.x - 8192) * 256 + threadIdx.x;
    const int s = idx >> 5, j = idx & 31;
    const float freq = powf(10000.f, -(float)(2 * j) * (1.f / 64.f));
    const float ang = (float)s * freq;
    cosT[idx] = cosf(ang);
    sinT[idx] = sinf(ang);
    return;
  }
  const size_t i = ((size_t)blockIdx.x * 256 + threadIdx.x) * 4;
  const float* src; unsigned short* dst; size_t off;
  if (i < 4194304)      { src = x;  dst = xb;              off = i; }
  else if (i < 5242880) { src = wq; dst = wqkv;            off = i - 4194304; }
  else if (i < 6291456) { src = wk; dst = wqkv + 1048576;  off = i - 5242880; }
  else if (i < 7340032) { src = wv; dst = wqkv + 2097152;  off = i - 6291456; }
  else                  { src = wo; dst = wob;             off = i - 7340032; }
  f32x4 v = *(const f32x4*)(src + off);
  ushort4v o;
  o[0] = f2bf(v[0]); o[1] = f2bf(v[1]); o[2] = f2bf(v[2]); o[3] = f2bf(v[3]);
  *(ushort4v*)(dst + off) = o;
}

// ---------------- GEMM C = A @ B^T, A:(M,K) bf16, B:(N,K) bf16 ----------------
// 128x128 tile, BK=64, 256 threads (4 waves, 2x2 of 64x64), 16x16x32 MFMA.
// LDS XOR-swizzle ((row&7)<<4) with pre-swizzled global_load_lds source.
// EPI 0: QKV epilogue (bias + RoPE + scale on Q, writes Qr/Kr head-major, Vt d-major)
// EPI 1: bias + fp32 store
template <int EPI>
__global__ __launch_bounds__(256) void gemm_bt_k(
    const unsigned short* __restrict__ A, const unsigned short* __restrict__ B,
    int M, int N, int K,
    unsigned short* __restrict__ Qr, unsigned short* __restrict__ Kr,
    unsigned short* __restrict__ Vt,
    const float* __restrict__ bq, const float* __restrict__ bk,
    const float* __restrict__ bvv,
    const float* __restrict__ cosT, const float* __restrict__ sinT,
    float* __restrict__ Cout, const float* __restrict__ bias) {
  __shared__ char smem[32768];   // A tile 16KB | B tile 16KB
  const int t = threadIdx.x;
  const int wave = t >> 6, lane = t & 63;
  const int l15 = lane & 15, g = lane >> 4;
  const int nt = N >> 7;
  const int mb = (blockIdx.x / nt) << 7;
  const int nb = (blockIdx.x % nt) << 7;
  const int wm = (wave >> 1) << 6;
  const int wn = (wave & 1) << 6;

  const f32x4 zv = {0.f, 0.f, 0.f, 0.f};
  f32x4 acc[4][4];
#pragma unroll
  for (int i = 0; i < 4; i++)
#pragma unroll
    for (int j = 0; j < 4; j++) acc[i][j] = zv;

  for (int kt = 0; kt < K; kt += 64) {
#pragma unroll
    for (int i = 0; i < 4; i++) {
      const int lin = t * 16 + i * 4096;
      const int r = lin >> 7;
      const int cb = (lin & 127) ^ ((r & 7) << 4);   // pre-swizzled source col-byte
      gload16((const char*)A + ((size_t)(mb + r) * K + kt) * 2 + cb,
              smem + i * 4096 + wave * 1024);
      gload16((const char*)B + ((size_t)(nb + r) * K + kt) * 2 + cb,
              smem + 16384 + i * 4096 + wave * 1024);
    }
    __syncthreads();

    bf16x8 af[4][2], bfr[4][2];
    const int sw = (l15 & 7) << 4;
#pragma unroll
    for (int mf = 0; mf < 4; mf++) {
      const int r = wm + mf * 16 + l15;
      const int r2 = wn + mf * 16 + l15;
#pragma unroll
      for (int kf = 0; kf < 2; kf++) {
        af[mf][kf]  = *(const bf16x8*)(smem + r * 128 + ((kf * 64 + g * 16) ^ sw));
        bfr[mf][kf] = *(const bf16x8*)(smem + 16384 + r2 * 128 + ((kf * 64 + g * 16) ^ sw));
      }
    }
#pragma unroll
    for (int mf = 0; mf < 4; mf++)
#pragma unroll
      for (int nf = 0; nf < 4; nf++) {
        acc[mf][nf] = __builtin_amdgcn_mfma_f32_16x16x32_bf16(af[mf][0], bfr[nf][0], acc[mf][nf], 0, 0, 0);
        acc[mf][nf] = __builtin_amdgcn_mfma_f32_16x16x32_bf16(af[mf][1], bfr[nf][1], acc[mf][nf], 0, 0, 0);
      }
    __syncthreads();
  }

  // epilogue: lane element (mf,nf,r): row = mb+wm+mf*16+g*4+r, col = nb+wn+nf*16+l15
#pragma unroll
  for (int mf = 0; mf < 4; mf++) {
#pragma unroll
    for (int nf = 0; nf < 4; nf++) {
      const int row0 = mb + wm + mf * 16 + g * 4;
      const int col = nb + wn + nf * 16 + l15;
      if (EPI == 1) {
        const float bsv = bias[col];
#pragma unroll
        for (int r = 0; r < 4; r++)
          Cout[(size_t)(row0 + r) * N + col] = acc[mf][nf][r] + bsv;
      } else {
        const int region = col >> 10;           // uniform per block (128 | 1024)
        const int cc = col & 1023;
        const int h = cc >> 6, d = cc & 63;
        const float bias_v = (region == 0 ? bq : (region == 1 ? bk : bvv))[cc];
        if (region < 2) {
          unsigned short* Ob = (region == 0 ? Qr : Kr);
          // Q gets 1/sqrt(64) * log2(e) baked in (flash works in exp2 domain)
          const float scl = (region == 0) ? 0.180336880111120425f : 1.0f;
#pragma unroll
          for (int r = 0; r < 4; r++) {
            const int row = row0 + r;
            const int s = row & 2047;
            const int b = row >> 11;
            const float v = acc[mf][nf][r] + bias_v;
            const float p = __shfl_xor(v, 1);
            const float c = cosT[s * 32 + (d >> 1)];
            const float sn = sinT[s * 32 + (d >> 1)];
            float o = (d & 1) ? (v * c + p * sn) : (v * c - p * sn);
            o *= scl;
            Ob[((size_t)(b * 16 + h) * 2048 + s) * 64 + d] = f2bf(o);
          }
        } else {
          ushort4v w;
#pragma unroll
          for (int r = 0; r < 4; r++) w[r] = f2bf(acc[mf][nf][r] + bias_v);
          const int s = row0 & 2047;
          const int b = row0 >> 11;
          *(ushort4v*)(Vt + ((size_t)(b * 16 + h) * 64 + d) * 2048 + s) = w;
        }
      }
    }
  }
}

// ---------------- flash attention v4 ----------------
// 1024 blocks x 256 threads (4 waves). QBLK=64 (16 q-rows/wave), KVBLK=64.
// K-tile (64x64) + V^T-tile staged per block into LDS (global_load_lds,
// pre-swizzled source), double-buffered, 1 barrier/iter. 40KB LDS ->
// 4 blocks/CU, grid exactly 4/CU. XCD head-affinity: each XCD owns 4 heads.
// Swapped QK^T, exp2-domain softmax, defer-max, native bf16 cvt (v_cvt_pk).
__global__ __launch_bounds__(256, 4) void flash_k(
    const unsigned short* __restrict__ Qr, const unsigned short* __restrict__ Kr,
    const unsigned short* __restrict__ Vt, unsigned short* __restrict__ Oa) {
  __shared__ char smem[40960];   // [2][K 8KB | V 8KB] dbuf + 4 x 2KB P buffers
  const int bid = blockIdx.x;
  const int bh = ((bid & 7) << 2) | ((bid >> 3) & 3);   // XCD (bid&7) owns 4 heads
  const int qt = bid >> 5;                              // 0..31
  const int t = threadIdx.x;
  const int wave = t >> 6, lane = t & 63;
  const int l15 = lane & 15, g = lane >> 4;
  char* pbuf = smem + 32768 + wave * 2048;
  const int q0 = qt * 64 + wave * 16;
  const unsigned short* Qb = Qr + ((size_t)bh * 2048 + q0) * 64;
  const char* Kb = (const char*)(Kr + (size_t)bh * 2048 * 64);
  const char* Vb = (const char*)(Vt + (size_t)bh * 64 * 2048);

  const bf16x8 qf0 = *(const bf16x8*)(Qb + l15 * 64 + g * 8);
  const bf16x8 qf1 = *(const bf16x8*)(Qb + l15 * 64 + g * 8 + 32);

  const f32x4 zv = {0.f, 0.f, 0.f, 0.f};
  f32x4 ot[4];
#pragma unroll
  for (int i = 0; i < 4; i++) ot[i] = zv;
  float m = -1e30f, lsum = 0.f;
  const int sw = (l15 & 7) << 4;

  // prologue: stage tile 0 (256 thr x 16B x 2 rounds per 8KB tile)
#pragma unroll
  for (int i = 0; i < 2; i++) {
    const int lin = t * 16 + i * 4096;
    const int r = lin >> 7;
    const int cb = (lin & 127) ^ ((r & 7) << 4);
    gload16(Kb + (size_t)r * 128 + cb, smem + i * 4096 + wave * 1024);
    gload16(Vb + (size_t)r * 4096 + cb, smem + 8192 + i * 4096 + wave * 1024);
  }
  __syncthreads();

  for (int it = 0; it < 32; ++it) {
    const int cur = it & 1;
    const char* kb = smem + cur * 16384;
    const char* vb = kb + 8192;
    if (it < 31) {   // stage next tile (loads stay in flight through compute)
      const int kvn = (it + 1) << 6;
      char* kd = smem + (cur ^ 1) * 16384;
#pragma unroll
      for (int i = 0; i < 2; i++) {
        const int lin = t * 16 + i * 4096;
        const int r = lin >> 7;
        const int cb = (lin & 127) ^ ((r & 7) << 4);
        gload16(Kb + (size_t)(kvn + r) * 128 + cb, kd + i * 4096 + wave * 1024);
        gload16(Vb + (size_t)r * 4096 + kvn * 2 + cb, kd + 8192 + i * 4096 + wave * 1024);
      }
    }
    // --- K frags from LDS + QK^T: lane holds S[q=l15][kv = s*16 + g*4 + e] ---
    f32x4 st[4];
#pragma unroll
    for (int s = 0; s < 4; s++) {
      const int rb = (s * 16 + l15) * 128;
      const bf16x8 k0 = *(const bf16x8*)(kb + rb + ((g * 16) ^ sw));
      const bf16x8 k1 = *(const bf16x8*)(kb + rb + ((64 + g * 16) ^ sw));
      f32x4 a = __builtin_amdgcn_mfma_f32_16x16x32_bf16(k0, qf0, zv, 0, 0, 0);
      st[s] = __builtin_amdgcn_mfma_f32_16x16x32_bf16(k1, qf1, a, 0, 0, 0);
    }
    // --- per-q max: in-lane + 2 shfl across g-groups ---
    float tmax = st[0][0];
#pragma unroll
    for (int s = 0; s < 4; s++)
#pragma unroll
      for (int e = 0; e < 4; e++) tmax = fmaxf(tmax, st[s][e]);
    tmax = fmaxf(tmax, __shfl_xor(tmax, 16));
    tmax = fmaxf(tmax, __shfl_xor(tmax, 32));
    // --- defer-max: rescale only when some row grew past m+8 (exp2 domain) ---
    if (!__all(tmax <= m + 8.0f)) {
      const float mn = fmaxf(m, tmax);
      const float al = __builtin_amdgcn_exp2f(m - mn);
      lsum *= al;
#pragma unroll
      for (int i = 0; i < 4; i++) {
        ot[i][0] *= al; ot[i][1] *= al; ot[i][2] *= al; ot[i][3] *= al;
      }
      m = mn;
    }
    // --- P = exp2(S - m); partial sums per s (shorter dep chains) ---
    float ls[4];
#pragma unroll
    for (int s = 0; s < 4; s++) {
      ls[s] = 0.f;
#pragma unroll
      for (int e = 0; e < 4; e++) {
        const float p = __builtin_amdgcn_exp2f(st[s][e] - m);
        st[s][e] = p;
        ls[s] += p;
      }
    }
    lsum += (ls[0] + ls[1]) + (ls[2] + ls[3]);
    // --- P -> per-wave LDS [q=l15, 128B row][kv byte] ^ sw (native cvt_pk) ---
#pragma unroll
    for (int s = 0; s < 4; s++) {
      bf16x4 w;
#pragma unroll
      for (int e = 0; e < 4; e++) w[e] = (__bf16)st[s][e];
      *(bf16x4*)(pbuf + ((l15 * 128 + s * 32 + g * 8) ^ sw)) = w;
    }
    asm volatile("" ::: "memory");   // wave-synchronous write->read order
    // --- V frags from LDS + PV: O^T += V^T . P^T ---
#pragma unroll
    for (int h = 0; h < 2; h++) {
      const bf16x8 pb = *(const bf16x8*)(pbuf + ((l15 * 128 + h * 64 + g * 16) ^ sw));
#pragma unroll
      for (int dc = 0; dc < 4; dc++) {
        const bf16x8 va = *(const bf16x8*)(vb + (dc * 16 + l15) * 128 + ((h * 64 + g * 16) ^ sw));
        ot[dc] = __builtin_amdgcn_mfma_f32_16x16x32_bf16(va, pb, ot[dc], 0, 0, 0);
      }
    }
    __syncthreads();   // stage loads landed (implicit vmcnt drain) + cur free
  }
  lsum += __shfl_xor(lsum, 16);
  lsum += __shfl_xor(lsum, 32);
  const float inv = 1.f / lsum;
  const int b = bh >> 4, h = bh & 15;
  const size_t rowbase = ((size_t)(b * 2048 + q0 + l15)) * 1024 + h * 64;
#pragma unroll
  for (int dc = 0; dc < 4; dc++) {
    bf16x4 w;
#pragma unroll
    for (int r = 0; r < 4; r++) w[r] = (__bf16)(ot[dc][r] * inv);
    *(bf16x4*)(Oa + rowbase + dc * 16 + g * 4) = w;
  }
}

// ---------------- launch ----------------
extern "C" void kernel_launch(void* const* d_in, const int* in_sizes, int n_in,
                              void* d_out, int out_size, void* d_ws, size_t ws_size,
                              hipStream_t stream) {
  const float* x  = (const float*)d_in[0];
  const float* wq = (const float*)d_in[1];
  const float* bq = (const float*)d_in[2];
  const float* wk = (const float*)d_in[3];
  const float* bk = (const float*)d_in[4];
  const float* wv = (const float*)d_in[5];
  const float* bv = (const float*)d_in[6];
  const float* wo = (const float*)d_in[7];
  const float* bo = (const float*)d_in[8];
  float* out = (float*)d_out;
  char* ws = (char*)d_ws;

  unsigned short* xb   = (unsigned short*)(ws);              //  8 MB
  unsigned short* wqkv = (unsigned short*)(ws + 8388608);    //  6 MB
  unsigned short* wob  = (unsigned short*)(ws + 14680064);   //  2 MB
  float* cosT          = (float*)(ws + 16777216);            // 256 KB
  float* sinT          = (float*)(ws + 17039360);            // 256 KB
  unsigned short* Qr   = (unsigned short*)(ws + 17301504);   //  8 MB (B,H,S,D)
  unsigned short* Kr   = (unsigned short*)(ws + 25690112);   //  8 MB (B,H,S,D)
  unsigned short* Vt   = (unsigned short*)(ws + 34078720);   //  8 MB (B,H,D,S)
  unsigned short* Oa   = (unsigned short*)(ws + 42467328);   //  8 MB (B,S,DM)

  convert_k<<<dim3(8448), dim3(256), 0, stream>>>(x, wq, wk, wv, wo, xb, wqkv, wob, cosT, sinT);
  gemm_bt_k<0><<<dim3(32 * 24), dim3(256), 0, stream>>>(
      xb, wqkv, 4096, 3072, 1024, Qr, Kr, Vt, bq, bk, bv, cosT, sinT,
      (float*)nullptr, (const float*)nullptr);
  flash_k<<<dim3(1024), dim3(256), 0, stream>>>(Qr, Kr, Vt, Oa);
  gemm_bt_k<1><<<dim3(32 * 8), dim3(256), 0, stream>>>(
      Oa, wob, 4096, 1024, 1024,
      (unsigned short*)nullptr, (unsigned short*)nullptr, (unsigned short*)nullptr,
      (const float*)nullptr, (const float*)nullptr, (const float*)nullptr,
      cosT, sinT, out, bo);
}